// Round 4
// baseline (235.819 us; speedup 1.0000x reference)
//
#include <hip/hip_runtime.h>
#include <hip/hip_bf16.h>

#define BGR 4096      // graphs per side
#define DIM 256
#define NG  16        // graphs per block
#define HS  257       // LDS row stride for rel_kernel (fp32)

typedef __bf16 bf16x8 __attribute__((ext_vector_type(8)));
typedef float  f32x4  __attribute__((ext_vector_type(4)));
typedef unsigned short u16x4 __attribute__((ext_vector_type(4)));
typedef unsigned short u16x8 __attribute__((ext_vector_type(8)));

__device__ __forceinline__ unsigned short f2b(float f) {
  unsigned u = __builtin_bit_cast(unsigned, f);
  u = (u + 0x7FFFu + ((u >> 16) & 1u)) >> 16;   // RNE
  return (unsigned short)u;
}

// ---------------------------------------------------------------------------
// Weight prep: W1b = [WO1;WI1] bf16 [128 rows][256 k]  (rows 0-63 WO1, 64-127 WI1)
//              W2b = [WO2|WI2] bf16 [256 rows][128 k]  (k 0-63 WO2, 64-127 WI2)
//              b1 = bO1+bI1 (f32[64]), b2 = bO2+bI2 (f32[256]).
// ---------------------------------------------------------------------------
__global__ void wcvt_kernel(
    const float* __restrict__ WO1, const float* __restrict__ WI1,
    const float* __restrict__ WO2, const float* __restrict__ WI2,
    const float* __restrict__ bO1, const float* __restrict__ bI1,
    const float* __restrict__ bO2, const float* __restrict__ bI2,
    unsigned short* __restrict__ W1b, unsigned short* __restrict__ W2b,
    float* __restrict__ b1, float* __restrict__ b2)
{
  const int i = blockIdx.x * 256 + threadIdx.x;   // 0..32767
  { int j = i >> 8, k = i & 255;
    float v = (j < 64) ? WO1[j * 256 + k] : WI1[(j - 64) * 256 + k];
    W1b[i] = f2b(v); }
  { int j = i >> 7, k = i & 127;
    float v = (k < 64) ? WO2[j * 64 + k] : WI2[j * 64 + (k - 64)];
    W2b[i] = f2b(v); }
  if (i < 64)  b1[i] = bO1[i] + bI1[i];
  if (i < 256) b2[i] = bO2[i] + bI2[i];
}

// ---------------------------------------------------------------------------
// Persistent-block fused CompGCN: 512 blocks (2/CU), NG=16 graphs each.
// Weights in VGPRs (loaded once). E prefetched to regs (pipeline). M in regs.
// 2 barriers per graph.
//
// LDS (44800 B):
//   [0,     16896) Ebf 32 x 528B  (bf16 E tile)
//   [16896, 27136) YT  128 x 80B  ([j][node]); rows 0-63 reused as H1T (wave-local)
//   [27136, 35840) A2  32 x 272B  ([dst][Ain(64)|Aout(64)])
//   [35840, 44800) Cc  2 x 4480B: [32x33 int counts][deg_in 32][deg_out 32][pad]
// ---------------------------------------------------------------------------
#define OFF_EB 0
#define OFF_YT 16896
#define OFF_A2 27136
#define OFF_CC 35840

__global__ __launch_bounds__(256, 2) void graph_emb_kernel(
    const float* __restrict__ subj_embs, const float* __restrict__ obj_embs,
    const int* __restrict__ subj_src, const int* __restrict__ subj_dst,
    const int* __restrict__ obj_src, const int* __restrict__ obj_dst,
    const unsigned short* __restrict__ W1b, const unsigned short* __restrict__ W2b,
    const float* __restrict__ b1, const float* __restrict__ b2,
    float* __restrict__ g_out /* [2*BGR, 256] */)
{
  __shared__ __align__(16) unsigned char S[44800];

  const int t = threadIdx.x;
  const int w = t >> 6;
  const int l = t & 63, ln16 = l & 15, kg = l >> 4;
  const int side = blockIdx.x >> 8;
  const int g0 = (blockIdx.x & 255) << 4;

  const float* __restrict__ embs = side ? obj_embs : subj_embs;
  const int* __restrict__ srcp = side ? obj_src : subj_src;
  const int* __restrict__ dstp = side ? obj_dst : subj_dst;

  // ---- Load loop-invariant weights into registers (once per block) ----
  bf16x8 wB0[8], wB1[8];
  {
    const unsigned short* p0 = W1b + ((16 * w + ln16) << 8) + (kg << 3);
    const unsigned short* p1 = W1b + ((64 + 16 * w + ln16) << 8) + (kg << 3);
    #pragma unroll
    for (int ks = 0; ks < 8; ks++) {
      wB0[ks] = *(const bf16x8*)(p0 + (ks << 5));
      wB1[ks] = *(const bf16x8*)(p1 + (ks << 5));
    }
  }
  bf16x8 wA2[4][4];
  #pragma unroll
  for (int mt = 0; mt < 4; mt++) {
    const unsigned short* p = W2b + (((w << 6) + (mt << 4) + ln16) << 7) + (kg << 3);
    #pragma unroll
    for (int ks = 0; ks < 4; ks++) wA2[mt][ks] = *(const bf16x8*)(p + (ks << 5));
  }
  const float b1j = b1[16 * w + ln16];
  float4 b2v[4];
  #pragma unroll
  for (int mt = 0; mt < 4; mt++)
    b2v[mt] = *(const float4*)(b2 + (w << 6) + (mt << 4) + (kg << 2));

  // ---- Prologue: zero Cc[0], load edges(0) + E(0), count edges(0) ----
  float4 pf[2][8];
  int esr[2], edr[2];
  {
    int4 z4 = {0, 0, 0, 0};
    for (int i = t; i < 280; i += 256) ((int4*)(S + OFF_CC))[i] = z4;
    if (t < 128) {
      esr[0] = srcp[(g0 << 7) + t] & 31;
      edr[0] = dstp[(g0 << 7) + t] & 31;
    }
    const float* eb = embs + ((size_t)(g0 << 5) + (t >> 3)) * DIM + ((t & 7) << 5);
    #pragma unroll
    for (int i = 0; i < 8; i++) pf[0][i] = ((const float4*)eb)[i];
    __syncthreads();
    if (t < 128) {
      int* cb = (int*)(S + OFF_CC);
      atomicAdd(&cb[edr[0] * 33 + esr[0]], 1);
      atomicAdd(&cb[1056 + edr[0]], 1);
      atomicAdd(&cb[1088 + esr[0]], 1);
    }
  }

  #pragma unroll 2
  for (int g = 0; g < NG; g++) {
    const int cur = g & 1, nxt = cur ^ 1;
    const int gg = g0 + g;

    // ---- convert E regs -> Ebf (bf16, 528B stride) ----
    {
      unsigned short* erow = (unsigned short*)(S + OFF_EB + (t >> 3) * 528) + ((t & 7) << 5);
      #pragma unroll
      for (int i = 0; i < 4; i++) {
        float4 a = pf[cur][2 * i], b = pf[cur][2 * i + 1];
        u16x8 pk = { f2b(a.x), f2b(a.y), f2b(a.z), f2b(a.w),
                     f2b(b.x), f2b(b.y), f2b(b.z), f2b(b.w) };
        *(u16x8*)(erow + (i << 3)) = pk;
      }
    }
    __syncthreads();   // BAR1: Ebf ready; prev-iter atomics complete

    // ---- issue prefetch for g+1 (overlaps whole compute chain) ----
    if (g + 1 < NG) {
      if (t < 128) {
        esr[nxt] = srcp[((gg + 1) << 7) + t] & 31;
        edr[nxt] = dstp[((gg + 1) << 7) + t] & 31;
      }
      const float* eb = embs + ((size_t)((gg + 1) << 5) + (t >> 3)) * DIM + ((t & 7) << 5);
      #pragma unroll
      for (int i = 0; i < 8; i++) pf[nxt][i] = ((const float4*)eb)[i];
    }

    // ---- zero Cc[nxt] for next graph ----
    {
      int4 z4 = {0, 0, 0, 0};
      for (int i = t; i < 280; i += 256) ((int4*)(S + OFF_CC + nxt * 4480))[i] = z4;
    }

    // ---- build M fragments in registers (per-lane, exact need) ----
    bf16x8 m1a, m1b, m2a, m2b;
    {
      const int* cb = (const int*)(S + OFF_CC + cur * 4480);
      const int r0 = ln16, r1 = 16 + ln16, k0 = kg << 3;
      const float fi0 = 1.0f / fmaxf((float)cb[1056 + r0], 1.0f);
      const float fi1 = 1.0f / fmaxf((float)cb[1056 + r1], 1.0f);
      const float fo0 = 1.0f / fmaxf((float)cb[1088 + r0], 1.0f);
      const float fo1 = 1.0f / fmaxf((float)cb[1088 + r1], 1.0f);
      u16x8 t1a, t1b, t2a, t2b;
      #pragma unroll
      for (int i = 0; i < 8; i++) {
        t1a[i] = f2b((float)cb[r0 * 33 + k0 + i] * fi0);
        t1b[i] = f2b((float)cb[r1 * 33 + k0 + i] * fi1);
        t2a[i] = f2b((float)cb[(k0 + i) * 33 + r0] * fo0);
        t2b[i] = f2b((float)cb[(k0 + i) * 33 + r1] * fo1);
      }
      m1a = __builtin_bit_cast(bf16x8, t1a);
      m1b = __builtin_bit_cast(bf16x8, t1b);
      m2a = __builtin_bit_cast(bf16x8, t2a);
      m2b = __builtin_bit_cast(bf16x8, t2b);
    }

    // ---- gemm0: Y = E @ W1catT -> YT[j][node] (wave-local j map) ----
    {
      f32x4 a00 = {0,0,0,0}, a01 = {0,0,0,0}, a10 = {0,0,0,0}, a11 = {0,0,0,0};
      const unsigned char* ea = S + OFF_EB + ln16 * 528 + (kg << 4);
      #pragma unroll
      for (int ks = 0; ks < 8; ks++) {
        bf16x8 A0 = *(const bf16x8*)(ea + (ks << 6));
        bf16x8 A1 = *(const bf16x8*)(ea + 16 * 528 + (ks << 6));
        a00 = __builtin_amdgcn_mfma_f32_16x16x32_bf16(A0, wB0[ks], a00, 0, 0, 0);
        a01 = __builtin_amdgcn_mfma_f32_16x16x32_bf16(A0, wB1[ks], a01, 0, 0, 0);
        a10 = __builtin_amdgcn_mfma_f32_16x16x32_bf16(A1, wB0[ks], a10, 0, 0, 0);
        a11 = __builtin_amdgcn_mfma_f32_16x16x32_bf16(A1, wB1[ks], a11, 0, 0, 0);
      }
      f32x4 av[4] = {a00, a01, a10, a11};
      #pragma unroll
      for (int mt = 0; mt < 2; mt++)
        #pragma unroll
        for (int nt = 0; nt < 2; nt++) {
          f32x4 c = av[mt * 2 + nt];
          const int jrow = (nt ? 64 : 0) + 16 * w + ln16;
          u16x4 pk = { f2b(c[0]), f2b(c[1]), f2b(c[2]), f2b(c[3]) };
          *(u16x4*)(S + OFF_YT + jrow * 80 + (mt << 5) + (kg << 3)) = pk;
        }
    }

    // ---- step1: H1T[j][node] = relu(Ain@Yo + Aout@Yi + b1) (wave-local) ----
    {
      bf16x8 Byo = *(const bf16x8*)(S + OFF_YT + (16 * w + ln16) * 80 + (kg << 4));
      bf16x8 Byi = *(const bf16x8*)(S + OFF_YT + (64 + 16 * w + ln16) * 80 + (kg << 4));
      f32x4 z = {0,0,0,0};
      f32x4 c0 = __builtin_amdgcn_mfma_f32_16x16x32_bf16(m1a, Byo, z, 0, 0, 0);
      c0 = __builtin_amdgcn_mfma_f32_16x16x32_bf16(m2a, Byi, c0, 0, 0, 0);
      f32x4 c1 = __builtin_amdgcn_mfma_f32_16x16x32_bf16(m1b, Byo, z, 0, 0, 0);
      c1 = __builtin_amdgcn_mfma_f32_16x16x32_bf16(m2b, Byi, c1, 0, 0, 0);
      u16x4 p0 = { f2b(fmaxf(c0[0] + b1j, 0.f)), f2b(fmaxf(c0[1] + b1j, 0.f)),
                   f2b(fmaxf(c0[2] + b1j, 0.f)), f2b(fmaxf(c0[3] + b1j, 0.f)) };
      u16x4 p1 = { f2b(fmaxf(c1[0] + b1j, 0.f)), f2b(fmaxf(c1[1] + b1j, 0.f)),
                   f2b(fmaxf(c1[2] + b1j, 0.f)), f2b(fmaxf(c1[3] + b1j, 0.f)) };
      *(u16x4*)(S + OFF_YT + (16 * w + ln16) * 80 + (kg << 3)) = p0;       // nodes 0-15
      *(u16x4*)(S + OFF_YT + (16 * w + ln16) * 80 + 32 + (kg << 3)) = p1;  // nodes 16-31
    }

    // ---- step2: A2[dst][Ain@H1 | Aout@H1] (wave-local reads) ----
    {
      bf16x8 Ah = *(const bf16x8*)(S + OFF_YT + (16 * w + ln16) * 80 + (kg << 4));
      f32x4 z = {0,0,0,0};
      bf16x8 Bm[4] = {m1a, m1b, m2a, m2b};
      #pragma unroll
      for (int half = 0; half < 2; half++)
        #pragma unroll
        for (int nt = 0; nt < 2; nt++) {
          f32x4 c = __builtin_amdgcn_mfma_f32_16x16x32_bf16(Ah, Bm[half * 2 + nt], z, 0, 0, 0);
          u16x4 pk = { f2b(c[0]), f2b(c[1]), f2b(c[2]), f2b(c[3]) };
          *(u16x4*)(S + OFF_A2 + ((nt << 4) + ln16) * 272
                    + (half << 7) + (w << 5) + (kg << 3)) = pk;
        }
    }
    __syncthreads();   // BAR2: A2 ready

    // ---- count edges for g+1 (Cc[nxt] zeroed above, separated by BAR2) ----
    if (g + 1 < NG && t < 128) {
      int* cb = (int*)(S + OFF_CC + nxt * 4480);
      atomicAdd(&cb[edr[nxt] * 33 + esr[nxt]], 1);
      atomicAdd(&cb[1056 + edr[nxt]], 1);
      atomicAdd(&cb[1088 + esr[nxt]], 1);
    }

    // ---- step3: H2 = relu(A2 @ W2catT + b2), fused mean readout ----
    {
      f32x4 acc[4][2];
      #pragma unroll
      for (int mt = 0; mt < 4; mt++) { f32x4 z = {0,0,0,0}; acc[mt][0] = z; acc[mt][1] = z; }
      #pragma unroll
      for (int ks = 0; ks < 4; ks++) {
        bf16x8 B0 = *(const bf16x8*)(S + OFF_A2 + ln16 * 272 + (ks << 6) + (kg << 4));
        bf16x8 B1 = *(const bf16x8*)(S + OFF_A2 + (16 + ln16) * 272 + (ks << 6) + (kg << 4));
        #pragma unroll
        for (int mt = 0; mt < 4; mt++) {
          acc[mt][0] = __builtin_amdgcn_mfma_f32_16x16x32_bf16(wA2[mt][ks], B0, acc[mt][0], 0, 0, 0);
          acc[mt][1] = __builtin_amdgcn_mfma_f32_16x16x32_bf16(wA2[mt][ks], B1, acc[mt][1], 0, 0, 0);
        }
      }
      float* outp = g_out + ((size_t)(side * BGR + gg)) * DIM;
      #pragma unroll
      for (int mt = 0; mt < 4; mt++) {
        float s0 = fmaxf(acc[mt][0][0] + b2v[mt].x, 0.f) + fmaxf(acc[mt][1][0] + b2v[mt].x, 0.f);
        float s1 = fmaxf(acc[mt][0][1] + b2v[mt].y, 0.f) + fmaxf(acc[mt][1][1] + b2v[mt].y, 0.f);
        float s2 = fmaxf(acc[mt][0][2] + b2v[mt].z, 0.f) + fmaxf(acc[mt][1][2] + b2v[mt].z, 0.f);
        float s3 = fmaxf(acc[mt][0][3] + b2v[mt].w, 0.f) + fmaxf(acc[mt][1][3] + b2v[mt].w, 0.f);
        #pragma unroll
        for (int d = 1; d < 16; d <<= 1) {
          s0 += __shfl_xor(s0, d); s1 += __shfl_xor(s1, d);
          s2 += __shfl_xor(s2, d); s3 += __shfl_xor(s3, d);
        }
        if (ln16 == 0) {
          float4 o = { s0 * 0.03125f, s1 * 0.03125f, s2 * 0.03125f, s3 * 0.03125f };
          *(float4*)(outp + (w << 6) + (mt << 4) + (kg << 2)) = o;
        }
      }
    }
  }
}

// ---------------------------------------------------------------------------
// r_embs = relu(rel @ relW.T + relb). 16 rows per block. (fp32 VALU)
// ---------------------------------------------------------------------------
__global__ __launch_bounds__(256, 4) void rel_kernel(
    const float* __restrict__ rel, const float* __restrict__ relW,
    const float* __restrict__ relb, float* __restrict__ r_out)
{
  __shared__ float srel[16 * HS];
  const int t = threadIdx.x;
  const int b0 = blockIdx.x << 4;
  #pragma unroll
  for (int i = 0; i < 4; i++) {
    int f = (i << 8) + t;
    int r = f >> 6, k4 = f & 63;
    float4 x = *(const float4*)(rel + (size_t)(b0 + r) * DIM + (k4 << 2));
    float* d = &srel[r * HS + (k4 << 2)];
    d[0] = x.x; d[1] = x.y; d[2] = x.z; d[3] = x.w;
  }
  __syncthreads();
  const int r = t & 15, jg = t >> 4;
  const float* pa = &srel[r * HS];
  const float* w = relW + (size_t)(jg * 16) * DIM;
  float acc[16];
  #pragma unroll
  for (int jj = 0; jj < 16; jj++) acc[jj] = 0.f;
  for (int k0 = 0; k0 < DIM; k0 += 16) {
    float a[16];
    #pragma unroll
    for (int u = 0; u < 16; u++) a[u] = pa[k0 + u];
    #pragma unroll
    for (int jj = 0; jj < 16; jj++) {
      const float* wr = w + jj * DIM + k0;
      #pragma unroll
      for (int u = 0; u < 16; u += 4) {
        float4 wv = *(const float4*)(wr + u);
        acc[jj] += a[u]*wv.x + a[u+1]*wv.y + a[u+2]*wv.z + a[u+3]*wv.w;
      }
    }
  }
  float* outp = r_out + (size_t)(b0 + r) * DIM + jg * 16;
  #pragma unroll
  for (int jj = 0; jj < 16; jj++) outp[jj] = fmaxf(acc[jj] + relb[jg * 16 + jj], 0.f);
}

// ---------------------------------------------------------------------------
// Distances: pos = ||h+r-t||, neg = ||h[ch]+r-t[ct]||. One wave per triple.
// ---------------------------------------------------------------------------
__global__ __launch_bounds__(256) void dist_kernel(
    const float* __restrict__ hemb, const float* __restrict__ temb,
    const float* __restrict__ remb, const int* __restrict__ chx,
    const int* __restrict__ ctx, float* __restrict__ out)
{
  const int t = threadIdx.x;
  const int w = t >> 6, l = t & 63;
  const int b = (blockIdx.x << 2) + w;
  float4 h4 = *(const float4*)(hemb + (size_t)b * DIM + (l << 2));
  float4 r4 = *(const float4*)(remb + (size_t)b * DIM + (l << 2));
  float4 t4 = *(const float4*)(temb + (size_t)b * DIM + (l << 2));
  int hb = chx[b], tb = ctx[b];
  float4 hn = *(const float4*)(hemb + (size_t)hb * DIM + (l << 2));
  float4 tn = *(const float4*)(temb + (size_t)tb * DIM + (l << 2));
  float x0 = h4.x + r4.x - t4.x, x1 = h4.y + r4.y - t4.y;
  float x2 = h4.z + r4.z - t4.z, x3 = h4.w + r4.w - t4.w;
  float dp = x0*x0 + x1*x1 + x2*x2 + x3*x3;
  float y0 = hn.x + r4.x - tn.x, y1 = hn.y + r4.y - tn.y;
  float y2 = hn.z + r4.z - tn.z, y3 = hn.w + r4.w - tn.w;
  float dn = y0*y0 + y1*y1 + y2*y2 + y3*y3;
  #pragma unroll
  for (int off = 32; off >= 1; off >>= 1) {
    dp += __shfl_down(dp, off);
    dn += __shfl_down(dn, off);
  }
  if (l == 0) {
    out[b] = sqrtf(dp);
    out[BGR + b] = sqrtf(dn);
  }
}

extern "C" void kernel_launch(void* const* d_in, const int* in_sizes, int n_in,
                              void* d_out, int out_size, void* d_ws, size_t ws_size,
                              hipStream_t stream) {
  const float* subj_embs = (const float*)d_in[0];
  const float* obj_embs  = (const float*)d_in[1];
  const float* rel_tok   = (const float*)d_in[2];
  const int* subj_src = (const int*)d_in[3];
  const int* subj_dst = (const int*)d_in[4];
  const int* obj_src  = (const int*)d_in[5];
  const int* obj_dst  = (const int*)d_in[6];
  // d_in[7] = node_graph_ids (implicit by construction)
  const int* chx = (const int*)d_in[8];
  const int* ctx = (const int*)d_in[9];
  const float* WO1 = (const float*)d_in[10];
  const float* bO1 = (const float*)d_in[11];
  const float* WI1 = (const float*)d_in[12];
  const float* bI1 = (const float*)d_in[13];
  const float* WO2 = (const float*)d_in[14];
  const float* bO2 = (const float*)d_in[15];
  const float* WI2 = (const float*)d_in[16];
  const float* bI2 = (const float*)d_in[17];
  const float* relW = (const float*)d_in[18];
  const float* relb = (const float*)d_in[19];

  float* g_embs = (float*)d_ws;                           // [8192,256] f32 = 8 MB
  float* r_embs = g_embs + (size_t)2 * BGR * DIM;         // [4096,256] f32 = 4 MB
  unsigned short* W1b = (unsigned short*)((char*)d_ws + 12582912);  // 64 KB
  unsigned short* W2b = W1b + 32768;                                // 64 KB
  float* b1 = (float*)((char*)d_ws + 12713984);                     // 256 B
  float* b2 = b1 + 64;                                              // 1 KB
  float* out = (float*)d_out;                             // [8192]: pos | neg

  wcvt_kernel<<<128, 256, 0, stream>>>(WO1, WI1, WO2, WI2, bO1, bI1, bO2, bI2,
                                       W1b, W2b, b1, b2);
  graph_emb_kernel<<<512, 256, 0, stream>>>(
      subj_embs, obj_embs, subj_src, subj_dst, obj_src, obj_dst,
      W1b, W2b, b1, b2, g_embs);
  rel_kernel<<<BGR / 16, 256, 0, stream>>>(rel_tok, relW, relb, r_embs);
  dist_kernel<<<BGR / 4, 256, 0, stream>>>(
      g_embs, g_embs + (size_t)BGR * DIM, r_embs, chx, ctx, out);
}